// Round 11
// baseline (522.231 us; speedup 1.0000x reference)
//
#include <hip/hip_runtime.h>
#include <hip/hip_fp16.h>
#include <hip/hip_cooperative_groups.h>

namespace cg = cooperative_groups;

// ---------------------------------------------------------------------------
// MultiSourceGNNBlock: two independent 2-layer GAT stacks on shared input.
// R10: cooperative mega-kernel with RUNTIME-QUERIED grid size (R9 failed:
// hard-coded 1024 > runtime's co-residency limit -> launch error -> zeros).
// All phases grid-stride; plain 6-dispatch fallback if coop unavailable.
// ---------------------------------------------------------------------------

#define NEG_SLOPE 0.2f
#define ELLW 96
#define BK 64
#define HPAD 8
#define GROWS 16

typedef _Float16 half8 __attribute__((ext_vector_type(8)));
typedef _Float16 half4 __attribute__((ext_vector_type(4)));
typedef float floatx4 __attribute__((ext_vector_type(4)));

union SM {
    _Float16 hT[GROWS][BK + HPAD];   // gemm staging
    float2 pairs[4][8][10];          // attn pair broadcast
};

struct MegaArgs {
    const float* h0;
    const int *ei1, *ei2;
    const float *W10, *W11, *W20, *W21;
    const float *as10, *ad10, *b10, *as11, *ad11, *b11;
    const float *as20, *ad20, *b20, *as21, *ad21, *b21;
    _Float16 *Wt10, *Wt20, *Wt11, *Wt21;
    int *cnt, *slots;
    __half *xh1, *xh2;
    float *hbuf1, *hbuf2;
    float *alS1, *alD1, *alS2, *alD2;
    float *out0, *out1;
    int N, E1, E2;
};

// ---------------- phase 0: Wt transpose/convert + cnt zero (grid-stride) ----

__device__ __forceinline__ void phase0_body(const MegaArgs& a, int flat, int GT) {
    for (int i = flat; i < 2 * a.N; i += GT) a.cnt[i] = 0;
    for (int i = flat; i < 32768; i += GT) {          // layer0: 2 x 256x64
        int s = i >> 14, rem = i & 16383;
        int c = rem >> 6, k = rem & 63;
        const float* W = s ? a.W20 : a.W10;
        _Float16* Wt = s ? a.Wt20 : a.Wt10;
        Wt[c * 64 + k] = (_Float16)W[k * 256 + c];
    }
    for (int i = flat; i < 131072; i += GT) {         // layer1: 2 x 256x256
        int s = i >> 16, rem = i & 65535;
        int c = rem >> 8, k = rem & 255;
        const float* W = s ? a.W21 : a.W11;
        _Float16* Wt = s ? a.Wt21 : a.Wt11;
        Wt[c * 256 + k] = (_Float16)W[k * 256 + c];
    }
}

// ---------------- phase 1: ELL scatter (grid-stride) ------------------------

__device__ __forceinline__ void phase1_body(const MegaArgs& a, int flat, int GT) {
    int tot1 = a.E1 + a.N, tot2 = a.E2 + a.N;
    int tot = tot1 + tot2;
    for (int i = flat; i < tot; i += GT) {
        int s, j; const int* ei; int E;
        if (i < tot1) { s = 0; j = i;        ei = a.ei1; E = a.E1; }
        else          { s = 1; j = i - tot1; ei = a.ei2; E = a.E2; }
        int src, dst;
        if (j < E) { src = ei[j]; dst = ei[E + j]; }
        else       { src = dst = j - E; }
        int gg = s * a.N + dst;
        int pos = atomicAdd(&a.cnt[gg], 1);
        if (pos < ELLW) a.slots[(size_t)gg * ELLW + pos] = src;
    }
}

// ---------------- gemm tile: 16 rows x 256 cols, wave == head ----------------
// MFMA fragment/epilogue mapping identical to validated R8 (f=0 path).

__device__ __forceinline__ void gemm_tile(
        const float* __restrict__ h, const _Float16* __restrict__ Wt,
        const float* __restrict__ a_s, const float* __restrict__ a_d,
        __half* __restrict__ xh, float* __restrict__ alS, float* __restrict__ alD,
        int K, int row0, SM& sm) {
    int tid = threadIdx.x;
    int wave = tid >> 6, lane = tid & 63;
    int lo = lane & 15, hi = lane >> 4;
    int c0 = wave * 64;
    floatx4 acc[4] = {};
    int srow = tid >> 4, sseg = tid & 15;
    const float* hrow = h + (size_t)(row0 + srow) * K + sseg * 4;
    const _Float16* wbase = Wt + (size_t)c0 * K;

    for (int k0 = 0; k0 < K; k0 += BK) {
        __syncthreads();
        float4 hv = *(const float4*)(hrow + k0);
        half4 hh;
        hh[0] = (_Float16)hv.x; hh[1] = (_Float16)hv.y;
        hh[2] = (_Float16)hv.z; hh[3] = (_Float16)hv.w;
        *(half4*)&sm.hT[srow][sseg * 4] = hh;
        __syncthreads();
        half8 bf[4], af;
#pragma unroll
        for (int ks = 0; ks < 2; ks++) {
#pragma unroll
            for (int cf = 0; cf < 4; cf++)
                bf[cf] = *(const half8*)(wbase + (size_t)(cf * 16 + lo) * K
                                         + k0 + ks * 32 + hi * 8);
            af = *(const half8*)&sm.hT[lo][ks * 32 + hi * 8];
#pragma unroll
            for (int cf = 0; cf < 4; cf++)
                acc[cf] = __builtin_amdgcn_mfma_f32_16x16x32_f16(
                    af, bf[cf], acc[cf], 0, 0, 0);
        }
    }

    float asw[4], adw[4];
#pragma unroll
    for (int cf = 0; cf < 4; cf++) {
        asw[cf] = a_s[c0 + cf * 16 + lo];
        adw[cf] = a_d[c0 + cf * 16 + lo];
    }
#pragma unroll
    for (int r = 0; r < 4; r++) {
        int row = row0 + hi * 4 + r;
        float v0 = acc[0][r], v1 = acc[1][r], v2 = acc[2][r], v3 = acc[3][r];
        __half* xrow = &xh[(size_t)row * 256 + c0 + lo];
        xrow[0]  = __float2half(v0);
        xrow[16] = __float2half(v1);
        xrow[32] = __float2half(v2);
        xrow[48] = __float2half(v3);
        float s1 = v0 * asw[0] + v1 * asw[1] + v2 * asw[2] + v3 * asw[3];
        float s2 = v0 * adw[0] + v1 * adw[1] + v2 * adw[2] + v3 * adw[3];
#pragma unroll
        for (int off = 1; off < 16; off <<= 1) {
            s1 += __shfl_xor(s1, off);
            s2 += __shfl_xor(s2, off);
        }
        if (lo == 0) {
            alS[row * 4 + wave] = s1;
            alD[row * 4 + wave] = s2;
        }
    }
}

__device__ __forceinline__ void gemm_phase(const MegaArgs& a, int layer,
                                           SM& sm, int bid, int nb) {
    int half = a.N / GROWS, nt = half * 2;
    int K = layer ? 256 : 64;
    for (int u = bid; u < nt; u += nb) {
        int s = (u >= half);
        int bx = u - s * half;
        const float* h = layer ? (s ? a.hbuf2 : a.hbuf1) : a.h0;
        const _Float16* Wt = layer ? (s ? a.Wt21 : a.Wt11)
                                   : (s ? a.Wt20 : a.Wt10);
        const float* as_ = layer ? (s ? a.as21 : a.as11)
                                 : (s ? a.as20 : a.as10);
        const float* ad_ = layer ? (s ? a.ad21 : a.ad11)
                                 : (s ? a.ad20 : a.ad10);
        gemm_tile(h, Wt, as_, ad_, s ? a.xh2 : a.xh1,
                  s ? a.alS2 : a.alS1, s ? a.alD2 : a.alD1,
                  K, bx * GROWS, sm);
    }
}

// ---------------- attn node: R8 8-stream ILP, wave == head ------------------

__device__ __forceinline__ void attn_node(
        int g, const MegaArgs& a, const float* __restrict__ b1,
        const float* __restrict__ b2, float* __restrict__ o1,
        float* __restrict__ o2, int do_relu, SM& sm) {
    int tid = threadIdx.x;
    int h = tid >> 6, L = tid & 63, st = L >> 3, lc = L & 7;
    int s = (g >= a.N) ? 1 : 0;
    int dst = g - s * a.N;
    const __half* xh   = s ? a.xh2  : a.xh1;
    const float*  alS  = s ? a.alS2 : a.alS1;
    const float*  alD  = s ? a.alD2 : a.alD1;
    const float*  bias = s ? b2   : b1;
    float*        out  = s ? o2 : o1;

    int nd = a.cnt[g];
    if (nd > ELLW) nd = ELLW;
    const int* slots = a.slots + (size_t)g * ELLW;
    float ad = alD[dst * 4 + h];
    const char* xb = (const char*)xh + h * 128 + lc * 16;

    float acc[8] = {};
    float pden = 0.f;

    for (int c = 0; c < nd; c += 64) {
        int n = nd - c; if (n > 64) n = 64;
        int off = 0; float p = 0.f;
        if (L < n) {
            int src = slots[c + L];
            float t = alS[src * 4 + h] + ad;
            t = (t > 0.f) ? t : NEG_SLOPE * t;
            p = __expf(t);
            off = src * 512;
        }
        pden += p;
        sm.pairs[h][L & 7][L >> 3] = make_float2(__int_as_float(off), p);
        int iters = (n + 7) >> 3;
        for (int ii = 0; ii < iters; ii += 4) {
            float4 twoA = *(const float4*)&sm.pairs[h][st][ii];
            float4 twoB = *(const float4*)&sm.pairs[h][st][ii + 2];
            int   o0i = __float_as_int(twoA.x); float w0 = twoA.y;
            int   o1i = __float_as_int(twoA.z); float w1 = twoA.w;
            int   o2i = __float_as_int(twoB.x); float w2 = twoB.y;
            int   o3i = __float_as_int(twoB.z); float w3 = twoB.w;
            float4 r0 = *(const float4*)(xb + o0i);
            float4 r1 = *(const float4*)(xb + o1i);
            float4 r2 = *(const float4*)(xb + o2i);
            float4 r3 = *(const float4*)(xb + o3i);
            const __half2* q0 = (const __half2*)&r0;
            const __half2* q1 = (const __half2*)&r1;
            const __half2* q2 = (const __half2*)&r2;
            const __half2* q3 = (const __half2*)&r3;
#pragma unroll
            for (int k = 0; k < 4; k++) {
                acc[2 * k + 0] += (float)q0[k].x * w0;
                acc[2 * k + 1] += (float)q0[k].y * w0;
                acc[2 * k + 0] += (float)q1[k].x * w1;
                acc[2 * k + 1] += (float)q1[k].y * w1;
                acc[2 * k + 0] += (float)q2[k].x * w2;
                acc[2 * k + 1] += (float)q2[k].y * w2;
                acc[2 * k + 0] += (float)q3[k].x * w3;
                acc[2 * k + 1] += (float)q3[k].y * w3;
            }
        }
    }
#pragma unroll
    for (int k = 0; k < 8; k++) {
        acc[k] += __shfl_xor(acc[k], 8);
        acc[k] += __shfl_xor(acc[k], 16);
        acc[k] += __shfl_xor(acc[k], 32);
    }
#pragma unroll
    for (int o2_ = 32; o2_ >= 1; o2_ >>= 1) pden += __shfl_xor(pden, o2_);

    if (st == 0) {
        float d = 1.0f / (pden + 1e-16f);
        int col = h * 64 + lc * 8;
        float4 bA = *(const float4*)&bias[col];
        float4 bB = *(const float4*)&bias[col + 4];
        float4 oA, oB;
        oA.x = acc[0] * d + bA.x; oA.y = acc[1] * d + bA.y;
        oA.z = acc[2] * d + bA.z; oA.w = acc[3] * d + bA.w;
        oB.x = acc[4] * d + bB.x; oB.y = acc[5] * d + bB.y;
        oB.z = acc[6] * d + bB.z; oB.w = acc[7] * d + bB.w;
        if (do_relu) {
            oA.x = fmaxf(oA.x, 0.f); oA.y = fmaxf(oA.y, 0.f);
            oA.z = fmaxf(oA.z, 0.f); oA.w = fmaxf(oA.w, 0.f);
            oB.x = fmaxf(oB.x, 0.f); oB.y = fmaxf(oB.y, 0.f);
            oB.z = fmaxf(oB.z, 0.f); oB.w = fmaxf(oB.w, 0.f);
        }
        *(float4*)&out[(size_t)dst * 256 + col] = oA;
        *(float4*)&out[(size_t)dst * 256 + col + 4] = oB;
    }
}

__device__ __forceinline__ void attn_phase(const MegaArgs& a, int layer,
                                           SM& sm, int bid, int nb) {
    const float* b1 = layer ? a.b11 : a.b10;
    const float* b2 = layer ? a.b21 : a.b20;
    float* o1 = layer ? a.out0 : a.hbuf1;
    float* o2 = layer ? a.out1 : a.hbuf2;
    int relu = layer ? 0 : 1;
    for (int g = bid; g < 2 * a.N; g += nb)
        attn_node(g, a, b1, b2, o1, o2, relu, sm);
}

// ---------------- mega kernel (cooperative) ----------------

__global__ __launch_bounds__(256, 4) void mega_kernel(MegaArgs a) {
    __shared__ SM sm;
    cg::grid_group grid = cg::this_grid();
    int flat = blockIdx.x * 256 + threadIdx.x;
    int GT = gridDim.x * 256;
    phase0_body(a, flat, GT);
    grid.sync();
    phase1_body(a, flat, GT);
    grid.sync();
    gemm_phase(a, 0, sm, blockIdx.x, gridDim.x);
    grid.sync();
    attn_phase(a, 0, sm, blockIdx.x, gridDim.x);
    grid.sync();
    gemm_phase(a, 1, sm, blockIdx.x, gridDim.x);
    grid.sync();
    attn_phase(a, 1, sm, blockIdx.x, gridDim.x);
}

// ---------------- fallback phase kernels (plain dispatches) ----------------

__global__ __launch_bounds__(256) void phase0_k(MegaArgs a) {
    phase0_body(a, blockIdx.x * 256 + threadIdx.x, gridDim.x * 256);
}
__global__ __launch_bounds__(256) void phase1_k(MegaArgs a) {
    phase1_body(a, blockIdx.x * 256 + threadIdx.x, gridDim.x * 256);
}
__global__ __launch_bounds__(256, 4) void gemm_k(MegaArgs a, int layer) {
    __shared__ SM sm;
    gemm_phase(a, layer, sm, blockIdx.x, gridDim.x);
}
__global__ __launch_bounds__(256, 4) void attn_k(MegaArgs a, int layer) {
    __shared__ SM sm;
    attn_phase(a, layer, sm, blockIdx.x, gridDim.x);
}

// ---------------------------------------------------------------------------

extern "C" void kernel_launch(void* const* d_in, const int* in_sizes, int n_in,
                              void* d_out, int out_size, void* d_ws, size_t ws_size,
                              hipStream_t stream) {
    const float* h0  = (const float*)d_in[0];
    const int*   ei1 = (const int*)d_in[1];
    const int*   ei2 = (const int*)d_in[2];

    const int N  = in_sizes[0] / 64;   // 8000 nodes
    const int E1 = in_sizes[1] / 2;
    const int E2 = in_sizes[2] / 2;

    char* base = (char*)d_ws;
    size_t off = 0;
    auto carve = [&](size_t bytes) -> void* {
        void* p = base + off;
        off += (bytes + 255) & ~(size_t)255;
        return p;
    };
    int* cnt     = (int*)carve((size_t)2 * N * 4);
    int* slots   = (int*)carve((size_t)2 * N * ELLW * 4);
    __half* xh1  = (__half*)carve((size_t)N * 256 * 2);
    __half* xh2  = (__half*)carve((size_t)N * 256 * 2);
    float* hbuf1 = (float*)carve((size_t)N * 256 * 4);
    float* hbuf2 = (float*)carve((size_t)N * 256 * 4);
    float* alS1  = (float*)carve((size_t)N * 4 * 4);
    float* alD1  = (float*)carve((size_t)N * 4 * 4);
    float* alS2  = (float*)carve((size_t)N * 4 * 4);
    float* alD2  = (float*)carve((size_t)N * 4 * 4);
    _Float16* Wt10 = (_Float16*)carve((size_t)256 * 64 * 2);
    _Float16* Wt20 = (_Float16*)carve((size_t)256 * 64 * 2);
    _Float16* Wt11 = (_Float16*)carve((size_t)256 * 256 * 2);
    _Float16* Wt21 = (_Float16*)carve((size_t)256 * 256 * 2);
    (void)ws_size; (void)n_in;

    MegaArgs a;
    a.h0 = h0; a.ei1 = ei1; a.ei2 = ei2;
    a.W10 = (const float*)d_in[3];  a.as10 = (const float*)d_in[4];
    a.ad10 = (const float*)d_in[5]; a.b10 = (const float*)d_in[6];
    a.W11 = (const float*)d_in[7];  a.as11 = (const float*)d_in[8];
    a.ad11 = (const float*)d_in[9]; a.b11 = (const float*)d_in[10];
    a.W20 = (const float*)d_in[11]; a.as20 = (const float*)d_in[12];
    a.ad20 = (const float*)d_in[13]; a.b20 = (const float*)d_in[14];
    a.W21 = (const float*)d_in[15]; a.as21 = (const float*)d_in[16];
    a.ad21 = (const float*)d_in[17]; a.b21 = (const float*)d_in[18];
    a.Wt10 = Wt10; a.Wt20 = Wt20; a.Wt11 = Wt11; a.Wt21 = Wt21;
    a.cnt = cnt; a.slots = slots;
    a.xh1 = xh1; a.xh2 = xh2;
    a.hbuf1 = hbuf1; a.hbuf2 = hbuf2;
    a.alS1 = alS1; a.alD1 = alD1; a.alS2 = alS2; a.alD2 = alD2;
    a.out0 = (float*)d_out; a.out1 = (float*)d_out + (size_t)N * 256;
    a.N = N; a.E1 = E1; a.E2 = E2;

    // ---- decide launch path via host-side queries (capture-safe, no enqueue)
    int dev = 0;
    hipGetDevice(&dev);
    int coopOK = 0;
    hipDeviceGetAttribute(&coopOK, hipDeviceAttributeCooperativeLaunch, dev);
    int cus = 0;
    hipDeviceGetAttribute(&cus, hipDeviceAttributeMultiprocessorCount, dev);
    int bpc = 0;
    hipOccupancyMaxActiveBlocksPerMultiprocessor(&bpc, mega_kernel, 256, 0);

    bool done = false;
    if (coopOK && bpc > 0 && cus > 0) {
        int grid = bpc * cus;
        if (grid > 1024) grid = 1024;
        void* kargs[] = { (void*)&a };
        if (hipLaunchCooperativeKernel((const void*)mega_kernel, dim3(grid),
                                       dim3(256), kargs, 0, stream) == hipSuccess)
            done = true;
    }
    if (!done) {
        int tot = (E1 + N) + (E2 + N);
        phase0_k<<<768, 256, 0, stream>>>(a);
        phase1_k<<<(tot + 255) / 256, 256, 0, stream>>>(a);
        gemm_k<<<(N / GROWS) * 2, 256, 0, stream>>>(a, 0);
        attn_k<<<2 * N, 256, 0, stream>>>(a, 0);
        gemm_k<<<(N / GROWS) * 2, 256, 0, stream>>>(a, 1);
        attn_k<<<2 * N, 256, 0, stream>>>(a, 1);
    }
}

// Round 12
// 121.611 us; speedup vs baseline: 4.2943x; 4.2943x over previous
//
#include <hip/hip_runtime.h>
#include <hip/hip_fp16.h>

// ---------------------------------------------------------------------------
// MultiSourceGNNBlock: two independent 2-layer GAT stacks on shared input.
// R11: revert R10 coop mega-kernel (785us — persistent grid killed attn
// parallelism + L2 locality). Base = proven R8 (131us). Deltas:
//  (1) ELL scatter merged into gemm0 dispatch (block-range split) -> 5 disp.
//  (2) hbuf fp16 (bit-equivalent for gemm1's fp16 MFMA; halves traffic).
// ---------------------------------------------------------------------------

#define NEG_SLOPE 0.2f
#define ELLW 96
#define BK 64
#define HPAD 8

typedef _Float16 half8 __attribute__((ext_vector_type(8)));
typedef float floatx4 __attribute__((ext_vector_type(4)));

struct Args {
    const float* h0;
    const int *ei1, *ei2;
    const float *W10, *W11, *W20, *W21;
    const float *as10, *ad10, *b10, *as11, *ad11, *b11;
    const float *as20, *ad20, *b20, *as21, *ad21, *b21;
    _Float16 *Wt10, *Wt20, *Wt11, *Wt21;
    int *cnt, *slots;
    _Float16 *xh1, *xh2;     // per-layer fp16 features (attn gather src)
    _Float16 *hb1, *hb2;     // fp16 hidden after layer0
    float *alS1, *alD1, *alS2, *alD2;
    float *out0, *out1;
    int N, E1, E2, GB0;      // GB0 = gemm0 block count (= (N/32)*2)
};

// ---------------- wt transpose/convert + cnt zeroing (R8) -------------------
// grid (256, 5, 2), block 64. Also zeroes cnt[2N] via flat id.

__global__ __launch_bounds__(64) void wt_zero_kernel(Args a) {
    int z = blockIdx.z, y = blockIdx.y, c = blockIdx.x;
    int t = threadIdx.x;
    int flat = ((z * gridDim.y + y) * gridDim.x + c) * 64 + t;
    if (flat < 2 * a.N) a.cnt[flat] = 0;
    if (y == 0) {
        const float* W  = z ? a.W20  : a.W10;
        _Float16*    Wt = z ? a.Wt20 : a.Wt10;
        Wt[(size_t)c * 64 + t] = (_Float16)W[(size_t)t * 256 + c];
    } else {
        int k = (y - 1) * 64 + t;
        const float* W  = z ? a.W21  : a.W11;
        _Float16*    Wt = z ? a.Wt21 : a.Wt11;
        Wt[(size_t)c * 256 + k] = (_Float16)W[(size_t)k * 256 + c];
    }
}

// ---------------- MFMA gemm tile: 32 rows x 256 cols, wave == head ----------
// Exact R8 fragment/epilogue mapping (validated). AHALF: A already fp16.

template<bool AHALF>
__device__ __forceinline__ void gemm_tile(
        const void* hv, const _Float16* __restrict__ Wt,
        const float* __restrict__ a_s, const float* __restrict__ a_d,
        _Float16* __restrict__ xh, float* __restrict__ alS,
        float* __restrict__ alD, int K, int row0,
        _Float16 (&hT)[32][BK + HPAD]) {
    int tid  = threadIdx.x;
    int wave = tid >> 6;          // == head
    int lane = tid & 63;
    int lo = lane & 15, hi = lane >> 4;
    int c0 = wave * 64;

    floatx4 acc[2][4] = {};       // [rowfrag][colfrag]

    int srow = tid >> 3, sseg = tid & 7;   // 32 rows x 8 k-octets
    const _Float16* wbase = Wt + (size_t)c0 * K;

    for (int k0 = 0; k0 < K; k0 += BK) {
        __syncthreads();
        if (AHALF) {
            const _Float16* hrow = (const _Float16*)hv
                                 + (size_t)(row0 + srow) * K + sseg * 8;
            *(half8*)&hT[srow][sseg * 8] = *(const half8*)(hrow + k0);
        } else {
            const float* hrow = (const float*)hv
                              + (size_t)(row0 + srow) * K + sseg * 8;
            float4 hv0 = *(const float4*)(hrow + k0);
            float4 hv1 = *(const float4*)(hrow + k0 + 4);
            half8 hh;
            hh[0] = (_Float16)hv0.x; hh[1] = (_Float16)hv0.y;
            hh[2] = (_Float16)hv0.z; hh[3] = (_Float16)hv0.w;
            hh[4] = (_Float16)hv1.x; hh[5] = (_Float16)hv1.y;
            hh[6] = (_Float16)hv1.z; hh[7] = (_Float16)hv1.w;
            *(half8*)&hT[srow][sseg * 8] = hh;
        }
        __syncthreads();

        half8 bf[2][4], af[2][2];
#pragma unroll
        for (int ks = 0; ks < 2; ks++) {
#pragma unroll
            for (int cf = 0; cf < 4; cf++)
                bf[ks][cf] = *(const half8*)(wbase + (size_t)(cf * 16 + lo) * K
                                             + k0 + ks * 32 + hi * 8);
#pragma unroll
            for (int f = 0; f < 2; f++)
                af[ks][f] = *(const half8*)&hT[f * 16 + lo][ks * 32 + hi * 8];
        }
#pragma unroll
        for (int ks = 0; ks < 2; ks++)
#pragma unroll
            for (int f = 0; f < 2; f++)
#pragma unroll
                for (int cf = 0; cf < 4; cf++)
                    acc[f][cf] = __builtin_amdgcn_mfma_f32_16x16x32_f16(
                        af[ks][f], bf[ks][cf], acc[f][cf], 0, 0, 0);
    }

    float asw[4], adw[4];
#pragma unroll
    for (int cf = 0; cf < 4; cf++) {
        asw[cf] = a_s[c0 + cf * 16 + lo];
        adw[cf] = a_d[c0 + cf * 16 + lo];
    }
#pragma unroll
    for (int f = 0; f < 2; f++) {
#pragma unroll
        for (int r = 0; r < 4; r++) {
            int row = row0 + f * 16 + hi * 4 + r;
            float v0 = acc[f][0][r], v1 = acc[f][1][r];
            float v2 = acc[f][2][r], v3 = acc[f][3][r];
            _Float16* xrow = &xh[(size_t)row * 256 + c0 + lo];
            xrow[0]  = (_Float16)v0;
            xrow[16] = (_Float16)v1;
            xrow[32] = (_Float16)v2;
            xrow[48] = (_Float16)v3;
            float s1 = v0 * asw[0] + v1 * asw[1] + v2 * asw[2] + v3 * asw[3];
            float s2 = v0 * adw[0] + v1 * adw[1] + v2 * adw[2] + v3 * adw[3];
#pragma unroll
            for (int off = 1; off < 16; off <<= 1) {
                s1 += __shfl_xor(s1, off);
                s2 += __shfl_xor(s2, off);
            }
            if (lo == 0) {
                alS[row * 4 + wave] = s1;
                alD[row * 4 + wave] = s2;
            }
        }
    }
}

// ---------------- gemm0 + ELL scatter, one dispatch --------------------------
// Blocks [0, GB0): gemm layer0 (K=64, fp32 A). Blocks [GB0, ...): scatter.

__global__ __launch_bounds__(256) void g0scat_kernel(Args a) {
    __shared__ _Float16 hT[32][BK + HPAD];
    int b = blockIdx.x;
    if (b < a.GB0) {
        int half_ = a.GB0 >> 1;
        int s = (b >= half_);
        int bx = b - s * half_;
        gemm_tile<false>(a.h0, s ? a.Wt20 : a.Wt10,
                         s ? a.as20 : a.as10, s ? a.ad20 : a.ad10,
                         s ? a.xh2 : a.xh1, s ? a.alS2 : a.alS1,
                         s ? a.alD2 : a.alD1, 64, bx * 32, hT);
    } else {
        int i = (b - a.GB0) * 256 + threadIdx.x;
        int tot1 = a.E1 + a.N, tot2 = a.E2 + a.N;
        if (i >= tot1 + tot2) return;
        int s, j; const int* ei; int E;
        if (i < tot1) { s = 0; j = i;        ei = a.ei1; E = a.E1; }
        else          { s = 1; j = i - tot1; ei = a.ei2; E = a.E2; }
        int src, dst;
        if (j < E) { src = ei[j]; dst = ei[E + j]; }
        else       { src = dst = j - E; }
        int gg = s * a.N + dst;
        int pos = atomicAdd(&a.cnt[gg], 1);
        if (pos < ELLW) a.slots[(size_t)gg * ELLW + pos] = src;
    }
}

__global__ __launch_bounds__(256) void gemm1_kernel(Args a) {
    __shared__ _Float16 hT[32][BK + HPAD];
    int half_ = a.GB0 >> 1;
    int b = blockIdx.x;
    int s = (b >= half_);
    int bx = b - s * half_;
    gemm_tile<true>(s ? a.hb2 : a.hb1, s ? a.Wt21 : a.Wt11,
                    s ? a.as21 : a.as11, s ? a.ad21 : a.ad11,
                    s ? a.xh2 : a.xh1, s ? a.alS2 : a.alS1,
                    s ? a.alD2 : a.alD1, 256, bx * 32, hT);
}

// ---------------- attn (R8 8-stream ILP), templated output ------------------

template<bool OUTHALF>
__device__ __forceinline__ void attn_impl(
        const Args& a, const float* __restrict__ b1, const float* __restrict__ b2,
        void* o1, void* o2, int do_relu) {
    __shared__ float2 pairs[4][8][10];
    int tid = threadIdx.x;
    int h = tid >> 6, L = tid & 63, st = L >> 3, lc = L & 7;
    int g = blockIdx.x;
    int s = (g >= a.N) ? 1 : 0;
    int dst = g - s * a.N;
    const _Float16* xh  = s ? a.xh2  : a.xh1;
    const float*  alS   = s ? a.alS2 : a.alS1;
    const float*  alD   = s ? a.alD2 : a.alD1;
    const float*  bias  = s ? b2 : b1;
    void*         out   = s ? o2 : o1;

    int nd = a.cnt[g];
    if (nd > ELLW) nd = ELLW;
    const int* slots = a.slots + (size_t)g * ELLW;
    float ad = alD[dst * 4 + h];
    const char* xb = (const char*)xh + h * 128 + lc * 16;

    float acc[8] = {};
    float pden = 0.f;

    for (int c = 0; c < nd; c += 64) {
        int n = nd - c; if (n > 64) n = 64;
        int off = 0; float p = 0.f;
        if (L < n) {
            int src = slots[c + L];
            float t = alS[src * 4 + h] + ad;
            t = (t > 0.f) ? t : NEG_SLOPE * t;
            p = __expf(t);
            off = src * 512;
        }
        pden += p;
        pairs[h][L & 7][L >> 3] = make_float2(__int_as_float(off), p);
        int iters = (n + 7) >> 3;
        for (int ii = 0; ii < iters; ii += 4) {
            float4 twoA = *(const float4*)&pairs[h][st][ii];
            float4 twoB = *(const float4*)&pairs[h][st][ii + 2];
            int   o0 = __float_as_int(twoA.x); float w0 = twoA.y;
            int   o1i = __float_as_int(twoA.z); float w1 = twoA.w;
            int   o2i = __float_as_int(twoB.x); float w2 = twoB.y;
            int   o3i = __float_as_int(twoB.z); float w3 = twoB.w;
            float4 r0 = *(const float4*)(xb + o0);
            float4 r1 = *(const float4*)(xb + o1i);
            float4 r2 = *(const float4*)(xb + o2i);
            float4 r3 = *(const float4*)(xb + o3i);
            const __half2* q0 = (const __half2*)&r0;
            const __half2* q1 = (const __half2*)&r1;
            const __half2* q2 = (const __half2*)&r2;
            const __half2* q3 = (const __half2*)&r3;
#pragma unroll
            for (int k = 0; k < 4; k++) {
                acc[2 * k + 0] += (float)q0[k].x * w0;
                acc[2 * k + 1] += (float)q0[k].y * w0;
                acc[2 * k + 0] += (float)q1[k].x * w1;
                acc[2 * k + 1] += (float)q1[k].y * w1;
                acc[2 * k + 0] += (float)q2[k].x * w2;
                acc[2 * k + 1] += (float)q2[k].y * w2;
                acc[2 * k + 0] += (float)q3[k].x * w3;
                acc[2 * k + 1] += (float)q3[k].y * w3;
            }
        }
    }
#pragma unroll
    for (int k = 0; k < 8; k++) {
        acc[k] += __shfl_xor(acc[k], 8);
        acc[k] += __shfl_xor(acc[k], 16);
        acc[k] += __shfl_xor(acc[k], 32);
    }
#pragma unroll
    for (int o2_ = 32; o2_ >= 1; o2_ >>= 1) pden += __shfl_xor(pden, o2_);

    if (st == 0) {
        float d = 1.0f / (pden + 1e-16f);
        int col = h * 64 + lc * 8;
        float4 bA = *(const float4*)&bias[col];
        float4 bB = *(const float4*)&bias[col + 4];
        float o[8];
        o[0] = acc[0] * d + bA.x; o[1] = acc[1] * d + bA.y;
        o[2] = acc[2] * d + bA.z; o[3] = acc[3] * d + bA.w;
        o[4] = acc[4] * d + bB.x; o[5] = acc[5] * d + bB.y;
        o[6] = acc[6] * d + bB.z; o[7] = acc[7] * d + bB.w;
        if (do_relu) {
#pragma unroll
            for (int k = 0; k < 8; k++) o[k] = fmaxf(o[k], 0.f);
        }
        if (OUTHALF) {
            half8 ov;
#pragma unroll
            for (int k = 0; k < 8; k++) ov[k] = (_Float16)o[k];
            *(half8*)((_Float16*)out + (size_t)dst * 256 + col) = ov;
        } else {
            float4 oA, oB;
            oA.x = o[0]; oA.y = o[1]; oA.z = o[2]; oA.w = o[3];
            oB.x = o[4]; oB.y = o[5]; oB.z = o[6]; oB.w = o[7];
            *(float4*)((float*)out + (size_t)dst * 256 + col) = oA;
            *(float4*)((float*)out + (size_t)dst * 256 + col + 4) = oB;
        }
    }
}

__global__ __launch_bounds__(256) void attn0_kernel(Args a) {
    attn_impl<true>(a, a.b10, a.b20, a.hb1, a.hb2, 1);
}
__global__ __launch_bounds__(256) void attn1_kernel(Args a) {
    attn_impl<false>(a, a.b11, a.b21, a.out0, a.out1, 0);
}

// ---------------------------------------------------------------------------

extern "C" void kernel_launch(void* const* d_in, const int* in_sizes, int n_in,
                              void* d_out, int out_size, void* d_ws, size_t ws_size,
                              hipStream_t stream) {
    const int N  = in_sizes[0] / 64;   // 8000 nodes
    const int E1 = in_sizes[1] / 2;
    const int E2 = in_sizes[2] / 2;

    char* base = (char*)d_ws;
    size_t off = 0;
    auto carve = [&](size_t bytes) -> void* {
        void* p = base + off;
        off += (bytes + 255) & ~(size_t)255;
        return p;
    };
    int* cnt        = (int*)carve((size_t)2 * N * 4);
    int* slots      = (int*)carve((size_t)2 * N * ELLW * 4);
    _Float16* xh1   = (_Float16*)carve((size_t)N * 256 * 2);
    _Float16* xh2   = (_Float16*)carve((size_t)N * 256 * 2);
    _Float16* hb1   = (_Float16*)carve((size_t)N * 256 * 2);
    _Float16* hb2   = (_Float16*)carve((size_t)N * 256 * 2);
    float* alS1     = (float*)carve((size_t)N * 4 * 4);
    float* alD1     = (float*)carve((size_t)N * 4 * 4);
    float* alS2     = (float*)carve((size_t)N * 4 * 4);
    float* alD2     = (float*)carve((size_t)N * 4 * 4);
    _Float16* Wt10  = (_Float16*)carve((size_t)256 * 64 * 2);
    _Float16* Wt20  = (_Float16*)carve((size_t)256 * 64 * 2);
    _Float16* Wt11  = (_Float16*)carve((size_t)256 * 256 * 2);
    _Float16* Wt21  = (_Float16*)carve((size_t)256 * 256 * 2);
    (void)ws_size; (void)n_in;

    Args a;
    a.h0 = (const float*)d_in[0];
    a.ei1 = (const int*)d_in[1];
    a.ei2 = (const int*)d_in[2];
    a.W10 = (const float*)d_in[3];  a.as10 = (const float*)d_in[4];
    a.ad10 = (const float*)d_in[5]; a.b10 = (const float*)d_in[6];
    a.W11 = (const float*)d_in[7];  a.as11 = (const float*)d_in[8];
    a.ad11 = (const float*)d_in[9]; a.b11 = (const float*)d_in[10];
    a.W20 = (const float*)d_in[11]; a.as20 = (const float*)d_in[12];
    a.ad20 = (const float*)d_in[13]; a.b20 = (const float*)d_in[14];
    a.W21 = (const float*)d_in[15]; a.as21 = (const float*)d_in[16];
    a.ad21 = (const float*)d_in[17]; a.b21 = (const float*)d_in[18];
    a.Wt10 = Wt10; a.Wt20 = Wt20; a.Wt11 = Wt11; a.Wt21 = Wt21;
    a.cnt = cnt; a.slots = slots;
    a.xh1 = xh1; a.xh2 = xh2; a.hb1 = hb1; a.hb2 = hb2;
    a.alS1 = alS1; a.alD1 = alD1; a.alS2 = alS2; a.alD2 = alD2;
    a.out0 = (float*)d_out; a.out1 = (float*)d_out + (size_t)N * 256;
    a.N = N; a.E1 = E1; a.E2 = E2;
    a.GB0 = (N / 32) * 2;

    int tot = (E1 + N) + (E2 + N);
    int scatterBlocks = (tot + 255) / 256;

    wt_zero_kernel<<<dim3(256, 5, 2), 64, 0, stream>>>(a);
    g0scat_kernel<<<a.GB0 + scatterBlocks, 256, 0, stream>>>(a);
    attn0_kernel<<<2 * N, 256, 0, stream>>>(a);
    gemm1_kernel<<<a.GB0, 256, 0, stream>>>(a);
    attn1_kernel<<<2 * N, 256, 0, stream>>>(a);
}

// Round 13
// 116.457 us; speedup vs baseline: 4.4843x; 1.0443x over previous
//
#include <hip/hip_runtime.h>
#include <hip/hip_fp16.h>

// ---------------------------------------------------------------------------
// MultiSourceGNNBlock: two independent 2-layer GAT stacks on shared input.
// R12: base = R11 (121.6us, 5 dispatches). Deltas:
//  (1) XCD-aware block swizzle in attn: g = (b&7)*(2N/8) + (b>>3) -> each
//      XCD's private L2 caches exactly one source's xh table (4MB = L2 size),
//      cutting HBM re-fetch of the gather tables.
//  (2) slots[L] prefetch overlapped with cnt load (one less serial L2 hop).
// ---------------------------------------------------------------------------

#define NEG_SLOPE 0.2f
#define ELLW 96
#define BK 64
#define HPAD 8

typedef _Float16 half8 __attribute__((ext_vector_type(8)));
typedef float floatx4 __attribute__((ext_vector_type(4)));

struct Args {
    const float* h0;
    const int *ei1, *ei2;
    const float *W10, *W11, *W20, *W21;
    const float *as10, *ad10, *b10, *as11, *ad11, *b11;
    const float *as20, *ad20, *b20, *as21, *ad21, *b21;
    _Float16 *Wt10, *Wt20, *Wt11, *Wt21;
    int *cnt, *slots;
    _Float16 *xh1, *xh2;     // per-layer fp16 features (attn gather src)
    _Float16 *hb1, *hb2;     // fp16 hidden after layer0
    float *alS1, *alD1, *alS2, *alD2;
    float *out0, *out1;
    int N, E1, E2, GB0;      // GB0 = gemm0 block count (= (N/32)*2)
};

// ---------------- wt transpose/convert + cnt zeroing -------------------------
// grid (256, 5, 2), block 64. Also zeroes cnt[2N] via flat id.

__global__ __launch_bounds__(64) void wt_zero_kernel(Args a) {
    int z = blockIdx.z, y = blockIdx.y, c = blockIdx.x;
    int t = threadIdx.x;
    int flat = ((z * gridDim.y + y) * gridDim.x + c) * 64 + t;
    if (flat < 2 * a.N) a.cnt[flat] = 0;
    if (y == 0) {
        const float* W  = z ? a.W20  : a.W10;
        _Float16*    Wt = z ? a.Wt20 : a.Wt10;
        Wt[(size_t)c * 64 + t] = (_Float16)W[(size_t)t * 256 + c];
    } else {
        int k = (y - 1) * 64 + t;
        const float* W  = z ? a.W21  : a.W11;
        _Float16*    Wt = z ? a.Wt21 : a.Wt11;
        Wt[(size_t)c * 256 + k] = (_Float16)W[(size_t)k * 256 + c];
    }
}

// ---------------- MFMA gemm tile: 32 rows x 256 cols, wave == head ----------
// Exact R8 fragment/epilogue mapping (validated). AHALF: A already fp16.

template<bool AHALF>
__device__ __forceinline__ void gemm_tile(
        const void* hv, const _Float16* __restrict__ Wt,
        const float* __restrict__ a_s, const float* __restrict__ a_d,
        _Float16* __restrict__ xh, float* __restrict__ alS,
        float* __restrict__ alD, int K, int row0,
        _Float16 (&hT)[32][BK + HPAD]) {
    int tid  = threadIdx.x;
    int wave = tid >> 6;          // == head
    int lane = tid & 63;
    int lo = lane & 15, hi = lane >> 4;
    int c0 = wave * 64;

    floatx4 acc[2][4] = {};       // [rowfrag][colfrag]

    int srow = tid >> 3, sseg = tid & 7;   // 32 rows x 8 k-octets
    const _Float16* wbase = Wt + (size_t)c0 * K;

    for (int k0 = 0; k0 < K; k0 += BK) {
        __syncthreads();
        if (AHALF) {
            const _Float16* hrow = (const _Float16*)hv
                                 + (size_t)(row0 + srow) * K + sseg * 8;
            *(half8*)&hT[srow][sseg * 8] = *(const half8*)(hrow + k0);
        } else {
            const float* hrow = (const float*)hv
                              + (size_t)(row0 + srow) * K + sseg * 8;
            float4 hv0 = *(const float4*)(hrow + k0);
            float4 hv1 = *(const float4*)(hrow + k0 + 4);
            half8 hh;
            hh[0] = (_Float16)hv0.x; hh[1] = (_Float16)hv0.y;
            hh[2] = (_Float16)hv0.z; hh[3] = (_Float16)hv0.w;
            hh[4] = (_Float16)hv1.x; hh[5] = (_Float16)hv1.y;
            hh[6] = (_Float16)hv1.z; hh[7] = (_Float16)hv1.w;
            *(half8*)&hT[srow][sseg * 8] = hh;
        }
        __syncthreads();

        half8 bf[2][4], af[2][2];
#pragma unroll
        for (int ks = 0; ks < 2; ks++) {
#pragma unroll
            for (int cf = 0; cf < 4; cf++)
                bf[ks][cf] = *(const half8*)(wbase + (size_t)(cf * 16 + lo) * K
                                             + k0 + ks * 32 + hi * 8);
#pragma unroll
            for (int f = 0; f < 2; f++)
                af[ks][f] = *(const half8*)&hT[f * 16 + lo][ks * 32 + hi * 8];
        }
#pragma unroll
        for (int ks = 0; ks < 2; ks++)
#pragma unroll
            for (int f = 0; f < 2; f++)
#pragma unroll
                for (int cf = 0; cf < 4; cf++)
                    acc[f][cf] = __builtin_amdgcn_mfma_f32_16x16x32_f16(
                        af[ks][f], bf[ks][cf], acc[f][cf], 0, 0, 0);
    }

    float asw[4], adw[4];
#pragma unroll
    for (int cf = 0; cf < 4; cf++) {
        asw[cf] = a_s[c0 + cf * 16 + lo];
        adw[cf] = a_d[c0 + cf * 16 + lo];
    }
#pragma unroll
    for (int f = 0; f < 2; f++) {
#pragma unroll
        for (int r = 0; r < 4; r++) {
            int row = row0 + f * 16 + hi * 4 + r;
            float v0 = acc[f][0][r], v1 = acc[f][1][r];
            float v2 = acc[f][2][r], v3 = acc[f][3][r];
            _Float16* xrow = &xh[(size_t)row * 256 + c0 + lo];
            xrow[0]  = (_Float16)v0;
            xrow[16] = (_Float16)v1;
            xrow[32] = (_Float16)v2;
            xrow[48] = (_Float16)v3;
            float s1 = v0 * asw[0] + v1 * asw[1] + v2 * asw[2] + v3 * asw[3];
            float s2 = v0 * adw[0] + v1 * adw[1] + v2 * adw[2] + v3 * adw[3];
#pragma unroll
            for (int off = 1; off < 16; off <<= 1) {
                s1 += __shfl_xor(s1, off);
                s2 += __shfl_xor(s2, off);
            }
            if (lo == 0) {
                alS[row * 4 + wave] = s1;
                alD[row * 4 + wave] = s2;
            }
        }
    }
}

// ---------------- gemm0 + ELL scatter, one dispatch --------------------------

__global__ __launch_bounds__(256) void g0scat_kernel(Args a) {
    __shared__ _Float16 hT[32][BK + HPAD];
    int b = blockIdx.x;
    if (b < a.GB0) {
        int half_ = a.GB0 >> 1;
        int s = (b >= half_);
        int bx = b - s * half_;
        gemm_tile<false>(a.h0, s ? a.Wt20 : a.Wt10,
                         s ? a.as20 : a.as10, s ? a.ad20 : a.ad10,
                         s ? a.xh2 : a.xh1, s ? a.alS2 : a.alS1,
                         s ? a.alD2 : a.alD1, 64, bx * 32, hT);
    } else {
        int i = (b - a.GB0) * 256 + threadIdx.x;
        int tot1 = a.E1 + a.N, tot2 = a.E2 + a.N;
        if (i >= tot1 + tot2) return;
        int s, j; const int* ei; int E;
        if (i < tot1) { s = 0; j = i;        ei = a.ei1; E = a.E1; }
        else          { s = 1; j = i - tot1; ei = a.ei2; E = a.E2; }
        int src, dst;
        if (j < E) { src = ei[j]; dst = ei[E + j]; }
        else       { src = dst = j - E; }
        int gg = s * a.N + dst;
        int pos = atomicAdd(&a.cnt[gg], 1);
        if (pos < ELLW) a.slots[(size_t)gg * ELLW + pos] = src;
    }
}

__global__ __launch_bounds__(256) void gemm1_kernel(Args a) {
    __shared__ _Float16 hT[32][BK + HPAD];
    int half_ = a.GB0 >> 1;
    int b = blockIdx.x;
    int s = (b >= half_);
    int bx = b - s * half_;
    gemm_tile<true>(s ? a.hb2 : a.hb1, s ? a.Wt21 : a.Wt11,
                    s ? a.as21 : a.as11, s ? a.ad21 : a.ad11,
                    s ? a.xh2 : a.xh1, s ? a.alS2 : a.alS1,
                    s ? a.alD2 : a.alD1, 256, bx * 32, hT);
}

// ---------------- attn (R8 8-stream ILP) + XCD swizzle ----------------------

template<bool OUTHALF>
__device__ __forceinline__ void attn_impl(
        const Args& a, const float* __restrict__ b1, const float* __restrict__ b2,
        void* o1, void* o2, int do_relu) {
    __shared__ float2 pairs[4][8][10];
    int tid = threadIdx.x;
    int h = tid >> 6, L = tid & 63, st = L >> 3, lc = L & 7;
    // XCD-aware swizzle: blockIdx%8 -> XCD; give each XCD a contiguous node
    // range so its L2 caches exactly one source's xh table.
    int b = blockIdx.x;
    int cpx = (2 * a.N) >> 3;                // 2N/8 nodes per XCD
    int g = (b & 7) * cpx + (b >> 3);
    int s = (g >= a.N) ? 1 : 0;
    int dst = g - s * a.N;
    const _Float16* xh  = s ? a.xh2  : a.xh1;
    const float*  alS   = s ? a.alS2 : a.alS1;
    const float*  alD   = s ? a.alD2 : a.alD1;
    const float*  bias  = s ? b2 : b1;
    void*         out   = s ? o2 : o1;

    const int* slots = a.slots + (size_t)g * ELLW;
    int pre = slots[L];                       // prefetch (ELLW=96>64: in-bounds)
    int nd = a.cnt[g];
    if (nd > ELLW) nd = ELLW;
    float ad = alD[dst * 4 + h];
    const char* xb = (const char*)xh + h * 128 + lc * 16;

    float acc[8] = {};
    float pden = 0.f;

    for (int c = 0; c < nd; c += 64) {
        int n = nd - c; if (n > 64) n = 64;
        int off = 0; float p = 0.f;
        if (L < n) {
            int src = (c == 0) ? pre : slots[c + L];
            float t = alS[src * 4 + h] + ad;
            t = (t > 0.f) ? t : NEG_SLOPE * t;
            p = __expf(t);
            off = src * 512;
        }
        pden += p;
        pairs[h][L & 7][L >> 3] = make_float2(__int_as_float(off), p);
        int iters = (n + 7) >> 3;
        for (int ii = 0; ii < iters; ii += 4) {
            float4 twoA = *(const float4*)&pairs[h][st][ii];
            float4 twoB = *(const float4*)&pairs[h][st][ii + 2];
            int   o0 = __float_as_int(twoA.x); float w0 = twoA.y;
            int   o1i = __float_as_int(twoA.z); float w1 = twoA.w;
            int   o2i = __float_as_int(twoB.x); float w2 = twoB.y;
            int   o3i = __float_as_int(twoB.z); float w3 = twoB.w;
            float4 r0 = *(const float4*)(xb + o0);
            float4 r1 = *(const float4*)(xb + o1i);
            float4 r2 = *(const float4*)(xb + o2i);
            float4 r3 = *(const float4*)(xb + o3i);
            const __half2* q0 = (const __half2*)&r0;
            const __half2* q1 = (const __half2*)&r1;
            const __half2* q2 = (const __half2*)&r2;
            const __half2* q3 = (const __half2*)&r3;
#pragma unroll
            for (int k = 0; k < 4; k++) {
                acc[2 * k + 0] += (float)q0[k].x * w0;
                acc[2 * k + 1] += (float)q0[k].y * w0;
                acc[2 * k + 0] += (float)q1[k].x * w1;
                acc[2 * k + 1] += (float)q1[k].y * w1;
                acc[2 * k + 0] += (float)q2[k].x * w2;
                acc[2 * k + 1] += (float)q2[k].y * w2;
                acc[2 * k + 0] += (float)q3[k].x * w3;
                acc[2 * k + 1] += (float)q3[k].y * w3;
            }
        }
    }
#pragma unroll
    for (int k = 0; k < 8; k++) {
        acc[k] += __shfl_xor(acc[k], 8);
        acc[k] += __shfl_xor(acc[k], 16);
        acc[k] += __shfl_xor(acc[k], 32);
    }
#pragma unroll
    for (int o2_ = 32; o2_ >= 1; o2_ >>= 1) pden += __shfl_xor(pden, o2_);

    if (st == 0) {
        float d = 1.0f / (pden + 1e-16f);
        int col = h * 64 + lc * 8;
        float4 bA = *(const float4*)&bias[col];
        float4 bB = *(const float4*)&bias[col + 4];
        float o[8];
        o[0] = acc[0] * d + bA.x; o[1] = acc[1] * d + bA.y;
        o[2] = acc[2] * d + bA.z; o[3] = acc[3] * d + bA.w;
        o[4] = acc[4] * d + bB.x; o[5] = acc[5] * d + bB.y;
        o[6] = acc[6] * d + bB.z; o[7] = acc[7] * d + bB.w;
        if (do_relu) {
#pragma unroll
            for (int k = 0; k < 8; k++) o[k] = fmaxf(o[k], 0.f);
        }
        if (OUTHALF) {
            half8 ov;
#pragma unroll
            for (int k = 0; k < 8; k++) ov[k] = (_Float16)o[k];
            *(half8*)((_Float16*)out + (size_t)dst * 256 + col) = ov;
        } else {
            float4 oA, oB;
            oA.x = o[0]; oA.y = o[1]; oA.z = o[2]; oA.w = o[3];
            oB.x = o[4]; oB.y = o[5]; oB.z = o[6]; oB.w = o[7];
            *(float4*)((float*)out + (size_t)dst * 256 + col) = oA;
            *(float4*)((float*)out + (size_t)dst * 256 + col + 4) = oB;
        }
    }
}

__global__ __launch_bounds__(256) void attn0_kernel(Args a) {
    attn_impl<true>(a, a.b10, a.b20, a.hb1, a.hb2, 1);
}
__global__ __launch_bounds__(256) void attn1_kernel(Args a) {
    attn_impl<false>(a, a.b11, a.b21, a.out0, a.out1, 0);
}

// ---------------------------------------------------------------------------

extern "C" void kernel_launch(void* const* d_in, const int* in_sizes, int n_in,
                              void* d_out, int out_size, void* d_ws, size_t ws_size,
                              hipStream_t stream) {
    const int N  = in_sizes[0] / 64;   // 8000 nodes
    const int E1 = in_sizes[1] / 2;
    const int E2 = in_sizes[2] / 2;

    char* base = (char*)d_ws;
    size_t off = 0;
    auto carve = [&](size_t bytes) -> void* {
        void* p = base + off;
        off += (bytes + 255) & ~(size_t)255;
        return p;
    };
    int* cnt        = (int*)carve((size_t)2 * N * 4);
    int* slots      = (int*)carve((size_t)2 * N * ELLW * 4);
    _Float16* xh1   = (_Float16*)carve((size_t)N * 256 * 2);
    _Float16* xh2   = (_Float16*)carve((size_t)N * 256 * 2);
    _Float16* hb1   = (_Float16*)carve((size_t)N * 256 * 2);
    _Float16* hb2   = (_Float16*)carve((size_t)N * 256 * 2);
    float* alS1     = (float*)carve((size_t)N * 4 * 4);
    float* alD1     = (float*)carve((size_t)N * 4 * 4);
    float* alS2     = (float*)carve((size_t)N * 4 * 4);
    float* alD2     = (float*)carve((size_t)N * 4 * 4);
    _Float16* Wt10  = (_Float16*)carve((size_t)256 * 64 * 2);
    _Float16* Wt20  = (_Float16*)carve((size_t)256 * 64 * 2);
    _Float16* Wt11  = (_Float16*)carve((size_t)256 * 256 * 2);
    _Float16* Wt21  = (_Float16*)carve((size_t)256 * 256 * 2);
    (void)ws_size; (void)n_in;

    Args a;
    a.h0 = (const float*)d_in[0];
    a.ei1 = (const int*)d_in[1];
    a.ei2 = (const int*)d_in[2];
    a.W10 = (const float*)d_in[3];  a.as10 = (const float*)d_in[4];
    a.ad10 = (const float*)d_in[5]; a.b10 = (const float*)d_in[6];
    a.W11 = (const float*)d_in[7];  a.as11 = (const float*)d_in[8];
    a.ad11 = (const float*)d_in[9]; a.b11 = (const float*)d_in[10];
    a.W20 = (const float*)d_in[11]; a.as20 = (const float*)d_in[12];
    a.ad20 = (const float*)d_in[13]; a.b20 = (const float*)d_in[14];
    a.W21 = (const float*)d_in[15]; a.as21 = (const float*)d_in[16];
    a.ad21 = (const float*)d_in[17]; a.b21 = (const float*)d_in[18];
    a.Wt10 = Wt10; a.Wt20 = Wt20; a.Wt11 = Wt11; a.Wt21 = Wt21;
    a.cnt = cnt; a.slots = slots;
    a.xh1 = xh1; a.xh2 = xh2; a.hb1 = hb1; a.hb2 = hb2;
    a.alS1 = alS1; a.alD1 = alD1; a.alS2 = alS2; a.alD2 = alD2;
    a.out0 = (float*)d_out; a.out1 = (float*)d_out + (size_t)N * 256;
    a.N = N; a.E1 = E1; a.E2 = E2;
    a.GB0 = (N / 32) * 2;

    int tot = (E1 + N) + (E2 + N);
    int scatterBlocks = (tot + 255) / 256;

    wt_zero_kernel<<<dim3(256, 5, 2), 64, 0, stream>>>(a);
    g0scat_kernel<<<a.GB0 + scatterBlocks, 256, 0, stream>>>(a);
    attn0_kernel<<<2 * N, 256, 0, stream>>>(a);
    gemm1_kernel<<<a.GB0, 256, 0, stream>>>(a);
    attn1_kernel<<<2 * N, 256, 0, stream>>>(a);
}